// Round 4
// baseline (314.613 us; speedup 1.0000x reference)
//
#include <hip/hip_runtime.h>
#include <math.h>

// ---------------- problem constants ----------------
#define T_LEN   32768
#define NK      192
#define NB      2
#define KDIR    48            // k < KDIR (j<=2): exact direct conv path
#define MAXM    56            // max half-support for direct path (true max 50)

struct SParams {
  int m1e[144];   // even-rounded half-support of stage-1 kernel, per k-48
  int voff[144];  // word offset of v-table per k-48
  int slot[144];  // complex slot count per k-48 (padded, zero-filled tail)
  int ab[9];      // A-arena word base per octave j-3
};

__device__ __forceinline__ int j2_of_q(int q) {
  // ceil(3.25 * 2^(q/16)) : {4,4,4,4,4,5,5,5,5,5,6,6,6,6,6,7}
  return 4 + (q >= 5) + (q >= 10) + (q >= 15);
}

// ---------------- v-table: v[m] = g1(m) * e^{i*omega*m} / N1 ----------------
__global__ __launch_bounds__(256) void k_vtab(float* __restrict__ ws, SParams P) {
  int ki = blockIdx.y;                 // 0..143
  int slotc = P.slot[ki];
  int e = blockIdx.x * 256 + threadIdx.x;
  if (e >= slotc) return;
  int M1e = P.m1e[ki];
  float* dst = ws + P.voff[ki];
  int nent = 2 * M1e + 2;              // m in [-M1e, M1e+1]
  if (e >= nent) { dst[2 * e] = 0.f; dst[2 * e + 1] = 0.f; return; }
  int k = ki + 48;
  int j = k >> 4, q = k & 15;
  float sig = 2.f * exp2f((float)(16 * j + q) * 0.0625f);
  float s1 = sig * 0.86602540378f;
  float gc = -0.5f / (s1 * s1);
  float om = 6.28318530718f / sig;
  float norm = 1.f / (2.50662827463f * s1 * erff((float)M1e / (1.41421356237f * s1)));
  float mm = (float)(e - M1e);
  float g = __expf(gc * mm * mm) * norm;
  float sn, cs; __sincosf(om * mm, &sn, &cs);
  dst[2 * e] = g * cs;
  dst[2 * e + 1] = g * sn;
}

// ---------------- stage 1, small octaves (j=3..6): 8 phases x 8 outputs/wave ----------------
__global__ __launch_bounds__(256) void k_s1_small(const float* __restrict__ x,
                                                  float* __restrict__ ws, SParams P) {
  int wid = blockIdx.x * 4 + (threadIdx.x >> 6);
  int lane = threadIdx.x & 63;
  int b = blockIdx.y;
  // regions (deepest first): j6 [0,1056) j5 [1056,3136) j4 [3136,7264) j3 [7264,15488)
  int j, base;
  if (wid < 1056)      { j = 6; base = 0; }
  else if (wid < 3136) { j = 5; base = 1056; }
  else if (wid < 7264) { j = 4; base = 3136; }
  else                 { j = 3; base = 7264; }
  int rem = wid - base;
  int tile = rem >> 4, q = rem & 15;
  int ki = 16 * (j - 3) + q;
  int d = 1 << j;
  int J2 = j2_of_q(q);
  int M1e = P.m1e[ki];
  const float* vt = ws + P.voff[ki];
  int r = lane >> 3, p = lane & 7;
  int nidx = tile * 8 + r;
  int nd = (nidx - J2) * d;
  int ustart = nd - M1e;                       // even
  int niter = (2 * M1e + 2 + 15) >> 4;
  int it0 = (-ustart - 15) >> 4; if (it0 < 0) it0 = 0;
  int itend = ((T_LEN - 1 - ustart) >> 4) + 1; if (niter > itend) niter = itend;
  const float* xb = x + b * T_LEN;
  float ar = 0.f, ai = 0.f;
  int u = ustart + 2 * p + 16 * it0;
  const float* vp = vt + 2 * (2 * p + 16 * it0);
  for (int it = it0; it < niter; ++it) {
    float4 v = *(const float4*)vp;
    float x0, x1;
    if ((unsigned)u <= (unsigned)(T_LEN - 2)) {
      float2 xv = *(const float2*)(xb + u);
      x0 = xv.x; x1 = xv.y;
    } else {
      x0 = ((unsigned)u < (unsigned)T_LEN) ? xb[u] : 0.f;
      int u1 = u + 1;
      x1 = ((unsigned)u1 < (unsigned)T_LEN) ? xb[u1] : 0.f;
    }
    ar += v.x * x0; ai += v.y * x0;
    ar += v.z * x1; ai += v.w * x1;
    u += 16; vp += 32;
  }
  ar += __shfl_xor(ar, 1, 64); ai += __shfl_xor(ai, 1, 64);
  ar += __shfl_xor(ar, 2, 64); ai += __shfl_xor(ai, 2, 64);
  ar += __shfl_xor(ar, 4, 64); ai += __shfl_xor(ai, 4, 64);
  if (p == 0) {
    // epilogue rotation: Ahat = A * e^{i*omega*nd}; omega*nd/2pi = nd * 2^-(j+1+q/16)
    float rev = (float)nd * exp2f(-(float)(16 * (j + 1) + q) * 0.0625f);
    rev -= floorf(rev);
    float sn, cs; __sincosf(rev * 6.28318530718f, &sn, &cs);
    float br = ar * cs - ai * sn;
    float bi = ar * sn + ai * cs;
    int Ncu = (32767 >> j) + 17;
    *(float2*)(ws + P.ab[j - 3] + ((q * 2 + b) * Ncu + nidx) * 2) = make_float2(br, bi);
  }
}

// ---------------- stage 1, large octaves (j=7..11): 64 phases x 1 output/wave ----------------
__global__ __launch_bounds__(256) void k_s1_large(const float* __restrict__ x,
                                                  float* __restrict__ ws, SParams P) {
  int wid = blockIdx.x * 4 + (threadIdx.x >> 6);
  int lane = threadIdx.x & 63;
  int b = blockIdx.y;
  // regions (deepest first): j11 [0,512) j10 [512,1280) j9 [1280,2560) j8 [2560,4864) j7 [4864,9216)
  int j, base;
  if (wid < 512)       { j = 11; base = 0; }
  else if (wid < 1280) { j = 10; base = 512; }
  else if (wid < 2560) { j = 9;  base = 1280; }
  else if (wid < 4864) { j = 8;  base = 2560; }
  else                 { j = 7;  base = 4864; }
  int rem = wid - base;
  int nidx = rem >> 4, q = rem & 15;
  int ki = 16 * (j - 3) + q;
  int d = 1 << j;
  int J2 = j2_of_q(q);
  int M1e = P.m1e[ki];
  const float* vt = ws + P.voff[ki];
  int nd = (nidx - J2) * d;
  int ustart = nd - M1e;
  int niter = (2 * M1e + 2 + 127) >> 7;
  int it0 = (-ustart - 127) >> 7; if (it0 < 0) it0 = 0;
  int itend = ((T_LEN - 1 - ustart) >> 7) + 1; if (niter > itend) niter = itend;
  const float* xb = x + b * T_LEN;
  float ar = 0.f, ai = 0.f;
  int u = ustart + 2 * lane + 128 * it0;
  const float* vp = vt + 2 * (2 * lane + 128 * it0);
  for (int it = it0; it < niter; ++it) {
    float4 v = *(const float4*)vp;
    float x0, x1;
    if ((unsigned)u <= (unsigned)(T_LEN - 2)) {
      float2 xv = *(const float2*)(xb + u);
      x0 = xv.x; x1 = xv.y;
    } else {
      x0 = ((unsigned)u < (unsigned)T_LEN) ? xb[u] : 0.f;
      int u1 = u + 1;
      x1 = ((unsigned)u1 < (unsigned)T_LEN) ? xb[u1] : 0.f;
    }
    ar += v.x * x0; ai += v.y * x0;
    ar += v.z * x1; ai += v.w * x1;
    u += 128; vp += 256;
  }
  ar += __shfl_xor(ar, 1, 64);  ai += __shfl_xor(ai, 1, 64);
  ar += __shfl_xor(ar, 2, 64);  ai += __shfl_xor(ai, 2, 64);
  ar += __shfl_xor(ar, 4, 64);  ai += __shfl_xor(ai, 4, 64);
  ar += __shfl_xor(ar, 8, 64);  ai += __shfl_xor(ai, 8, 64);
  ar += __shfl_xor(ar, 16, 64); ai += __shfl_xor(ai, 16, 64);
  ar += __shfl_xor(ar, 32, 64); ai += __shfl_xor(ai, 32, 64);
  if (lane == 0) {
    float rev = (float)nd * exp2f(-(float)(16 * (j + 1) + q) * 0.0625f);
    rev -= floorf(rev);
    float sn, cs; __sincosf(rev * 6.28318530718f, &sn, &cs);
    float br = ar * cs - ai * sn;
    float bi = ar * sn + ai * cs;
    int Ncu = (32767 >> j) + 17;
    *(float2*)(ws + P.ab[j - 3] + ((q * 2 + b) * Ncu + nidx) * 2) = make_float2(br, bi);
  }
}

// ---------------- stage 2: Gaussian interp of Ahat + modulus (rotation-free) ----------------
__global__ __launch_bounds__(256) void k_stage2(const float* __restrict__ ws,
                                                float* __restrict__ out, SParams P) {
  int k = KDIR + blockIdx.y;
  int j = k >> 4, q = k & 15;
  int b = blockIdx.z;
  int d = 1 << j;
  int J2 = j2_of_q(q);
  float sig = 2.f * exp2f((float)(16 * j + q) * 0.0625f);
  float s2 = sig * 0.5f;
  int Ncu = (32767 >> j) + 17;
  const float* A = ws + P.ab[j - 3] + (q * 2 + b) * Ncu * 2;
  int t = blockIdx.x * 256 + threadIdx.x;
  int nb = t >> j;
  int phi = t & (d - 1);
  int ntap = 2 * J2 + 1;
  float fd = (float)d;
  float inv2 = 1.f / (s2 * s2);
  float u0 = (float)(phi + J2 * d);
  float eg = __expf(-0.5f * u0 * u0 * inv2);
  float mf = __expf((fd * u0 - 0.5f * fd * fd) * inv2);
  float qf = __expf(-fd * fd * inv2);
  float Z = 0.f, sr = 0.f, si = 0.f;
  const float* Ap = A + 2 * nb;
  for (int rr = 0; rr < ntap; ++rr) {
    float2 a = *(const float2*)(Ap + 2 * rr);
    sr += eg * a.x;
    si += eg * a.y;
    Z += eg;
    eg *= mf; mf *= qf;
  }
  out[(size_t)(b * NK + k) * T_LEN + t] = sqrtf(sr * sr + si * si) / Z;
}

// ---------------- direct exact conv for j<=2 ----------------
__global__ __launch_bounds__(256) void k_direct(const float* __restrict__ x,
                                               const float* __restrict__ fr,
                                               const float* __restrict__ fi,
                                               float* __restrict__ out, int Lmax) {
  int k = blockIdx.y;
  int b = blockIdx.z;
  int t0 = blockIdx.x * 1024;
  int j = k >> 4, q = k & 15;
  int M = (int)ceil(6.0 * exp2((double)j + (double)q * 0.0625)) + 2; // >= true M; extra taps are 0
  int P = Lmax >> 1;
  __shared__ float xs[1024 + 2 * MAXM];
  __shared__ float frs[2 * MAXM + 1], fis[2 * MAXM + 1];
  int tid = threadIdx.x;
  int xlen = 1024 + 2 * M;
  const float* xb = x + b * T_LEN;
  for (int i = tid; i < xlen; i += 256) {
    int u = t0 - M + i;
    xs[i] = (u >= 0 && u < T_LEN) ? xb[u] : 0.f;
  }
  const float* frk = fr + (size_t)k * Lmax + (P - M);
  const float* fik = fi + (size_t)k * Lmax + (P - M);
  int tl = 2 * M + 1;
  for (int i = tid; i < tl; i += 256) { frs[i] = frk[i]; fis[i] = fik[i]; }
  __syncthreads();
  float ar[4] = {0.f, 0.f, 0.f, 0.f}, ai[4] = {0.f, 0.f, 0.f, 0.f};
  for (int tau = 0; tau < tl; ++tau) {
    float wr = frs[tau], wi = fis[tau];
    #pragma unroll
    for (int tt = 0; tt < 4; ++tt) {
      float xv = xs[tid + tt * 256 + tau];
      ar[tt] += wr * xv; ai[tt] += wi * xv;
    }
  }
  size_t ob = (size_t)(b * NK + k) * T_LEN + t0 + tid;
  #pragma unroll
  for (int tt = 0; tt < 4; ++tt)
    out[ob + tt * 256] = sqrtf(ar[tt] * ar[tt] + ai[tt] * ai[tt]);
}

// ---------------- launch ----------------
extern "C" void kernel_launch(void* const* d_in, const int* in_sizes, int n_in,
                              void* d_out, int out_size, void* d_ws, size_t ws_size,
                              hipStream_t stream) {
  const float* x  = (const float*)d_in[0];
  const float* fr = (const float*)d_in[1];
  const float* fi = (const float*)d_in[2];
  float* out = (float*)d_out;
  float* ws  = (float*)d_ws;
  int Lmax = in_sizes[1] / NK;   // 47069

  // host-side geometry (pure CPU math, deterministic, graph-capture-safe)
  SParams Pm;
  int cur = 0;
  for (int ki = 0; ki < 144; ++ki) {
    int j = (ki + 48) >> 4, q = ki & 15;
    double sig = 2.0 * exp2(((double)(16 * j + q)) / 16.0);
    double s1 = sig * 0.86602540378443864676;
    int M1 = (int)ceil(3.5 * s1);
    int M1e = (M1 + 1) & ~1;
    int R = (j >= 7) ? 128 : 16;
    int slotc = (2 * M1e + 2 + R - 1) & ~(R - 1);
    Pm.m1e[ki] = M1e;
    Pm.voff[ki] = cur;
    Pm.slot[ki] = slotc;
    cur += 2 * slotc;
  }
  for (int j = 3; j <= 11; ++j) {
    Pm.ab[j - 3] = cur;
    cur += 32 * ((32767 >> j) + 17) * 2;   // 16q * 2b * Ncu * 2 words
  }

  k_vtab<<<dim3(186, 144), dim3(256), 0, stream>>>(ws, Pm);
  k_s1_large<<<dim3(2304, NB), dim3(256), 0, stream>>>(x, ws, Pm);
  k_s1_small<<<dim3(3872, NB), dim3(256), 0, stream>>>(x, ws, Pm);
  k_direct<<<dim3(T_LEN / 1024, KDIR, NB), dim3(256), 0, stream>>>(x, fr, fi, out, Lmax);
  k_stage2<<<dim3(T_LEN / 256, NK - KDIR, NB), dim3(256), 0, stream>>>(ws, out, Pm);
}

// Round 5
// 291.139 us; speedup vs baseline: 1.0806x; 1.0806x over previous
//
#include <hip/hip_runtime.h>
#include <math.h>

// ---------------- problem constants ----------------
#define T_LEN   32768
#define NK      192
#define NB      2
#define KDIR    48            // k < KDIR (j<=2): exact direct conv path
#define MAXM    56            // max half-support for direct path (true max 50)
#define LBLK    34304         // large-path blocks (j=5..11), one output each
#define SBLK    3088          // small-path blocks (j=3,4), 4 waves x 8 outputs
#define GRIDX   (LBLK + SBLK) // 37392

struct SParams {
  int m1e[144];   // even half-support of stage-1 kernel per k-48
  int voff[144];  // v-table word offset per k-48
  int slot[144];  // padded complex tap count per k-48 (zero-filled tail)
  int ab[9];      // A-arena word base per octave j-3
};

__device__ __forceinline__ int j2_of_q(int q) {
  // ceil(3.25 * 2^(q/16)) : {4,4,4,4,4,5,5,5,5,5,6,6,6,6,6,7}
  return 4 + (q >= 5) + (q >= 10) + (q >= 15);
}

// ---------------- v-table: v[m] = g1(m) * e^{i*omega*m} / N1 ----------------
__global__ __launch_bounds__(256) void k_vtab(float* __restrict__ ws, SParams P) {
  int ki = blockIdx.y;                 // 0..143
  int slotc = P.slot[ki];
  int e = blockIdx.x * 256 + threadIdx.x;
  if (e >= slotc) return;
  int M1e = P.m1e[ki];
  float* dst = ws + P.voff[ki];
  int nent = 2 * M1e + 2;              // m in [-M1e, M1e+1]
  if (e >= nent) { dst[2 * e] = 0.f; dst[2 * e + 1] = 0.f; return; }
  int k = ki + 48;
  int j = k >> 4, q = k & 15;
  float sig = 2.f * exp2f((float)(16 * j + q) * 0.0625f);
  float s1 = sig * 0.86602540378f;
  float gc = -0.5f / (s1 * s1);
  float om = 6.28318530718f / sig;
  float norm = 1.f / (2.50662827463f * s1 * erff((float)M1e / (1.41421356237f * s1)));
  float mm = (float)(e - M1e);
  float g = __expf(gc * mm * mm) * norm;
  float sn, cs; __sincosf(om * mm, &sn, &cs);
  dst[2 * e] = g * cs;
  dst[2 * e + 1] = g * sn;
}

// ---------------- merged stage 1 ----------------
// Large path (j=5..11): one output per 256-thread block, 512 taps/iter, 4x unroll.
// Small path (j=3,4): wave = 8 phases x 8 outputs, 16 taps/iter, 4x unroll.
__global__ __launch_bounds__(256) void k_s1(const float* __restrict__ x,
                                            float* __restrict__ ws, SParams P) {
  __shared__ float red[8];
  int b = blockIdx.y;
  const float* xb = x + b * T_LEN;
  int bx = blockIdx.x;
  int tid = threadIdx.x;

  if (bx < LBLK) {
    // ---- large path ----
    int j, base;
    if (bx < 512)        { j = 11; base = 0; }
    else if (bx < 1280)  { j = 10; base = 512; }
    else if (bx < 2560)  { j = 9;  base = 1280; }
    else if (bx < 4864)  { j = 8;  base = 2560; }
    else if (bx < 9216)  { j = 7;  base = 4864; }
    else if (bx < 17664) { j = 6;  base = 9216; }
    else                 { j = 5;  base = 17664; }
    int rem = bx - base;
    int q = rem & 15, nidx = rem >> 4;
    int ki = 16 * (j - 3) + q;
    int d = 1 << j, J2 = j2_of_q(q);
    int M1e = P.m1e[ki];
    const float* vt = ws + P.voff[ki];
    int nd = (nidx - J2) * d;
    int ustart = nd - M1e;                  // even
    int it0 = (-ustart) >> 9; if (it0 < 0) it0 = 0;
    int itend = ((T_LEN - 1 - ustart) >> 9) + 1;
    int niter = P.slot[ki] >> 9; if (niter > itend) niter = itend;
    float ar = 0.f, ai = 0.f;
    int it = it0;
    for (; it + 4 <= niter; it += 4) {
      int mt0 = 2 * tid + (it << 9);
      float4 v0 = *(const float4*)(vt + 2 * mt0);
      float4 v1 = *(const float4*)(vt + 2 * (mt0 + 512));
      float4 v2 = *(const float4*)(vt + 2 * (mt0 + 1024));
      float4 v3 = *(const float4*)(vt + 2 * (mt0 + 1536));
      int u0 = ustart + mt0, u1 = u0 + 512, u2 = u0 + 1024, u3 = u0 + 1536;
      int c0 = min(max(u0, 0), T_LEN - 2), c1 = min(max(u1, 0), T_LEN - 2);
      int c2 = min(max(u2, 0), T_LEN - 2), c3 = min(max(u3, 0), T_LEN - 2);
      float2 p0 = *(const float2*)(xb + c0);
      float2 p1 = *(const float2*)(xb + c1);
      float2 p2 = *(const float2*)(xb + c2);
      float2 p3 = *(const float2*)(xb + c3);
      bool k0 = (unsigned)u0 <= (unsigned)(T_LEN - 2);
      bool k1 = (unsigned)u1 <= (unsigned)(T_LEN - 2);
      bool k2 = (unsigned)u2 <= (unsigned)(T_LEN - 2);
      bool k3 = (unsigned)u3 <= (unsigned)(T_LEN - 2);
      float x00 = k0 ? p0.x : 0.f, x01 = k0 ? p0.y : 0.f;
      float x10 = k1 ? p1.x : 0.f, x11 = k1 ? p1.y : 0.f;
      float x20 = k2 ? p2.x : 0.f, x21 = k2 ? p2.y : 0.f;
      float x30 = k3 ? p3.x : 0.f, x31 = k3 ? p3.y : 0.f;
      ar += v0.x * x00; ai += v0.y * x00; ar += v0.z * x01; ai += v0.w * x01;
      ar += v1.x * x10; ai += v1.y * x10; ar += v1.z * x11; ai += v1.w * x11;
      ar += v2.x * x20; ai += v2.y * x20; ar += v2.z * x21; ai += v2.w * x21;
      ar += v3.x * x30; ai += v3.y * x30; ar += v3.z * x31; ai += v3.w * x31;
    }
    for (; it < niter; ++it) {
      int mt = 2 * tid + (it << 9);
      float4 v = *(const float4*)(vt + 2 * mt);
      int u = ustart + mt;
      int uc = min(max(u, 0), T_LEN - 2);
      float2 p = *(const float2*)(xb + uc);
      bool ok = (unsigned)u <= (unsigned)(T_LEN - 2);
      float x0 = ok ? p.x : 0.f, x1 = ok ? p.y : 0.f;
      ar += v.x * x0; ai += v.y * x0; ar += v.z * x1; ai += v.w * x1;
    }
    ar += __shfl_xor(ar, 1, 64);  ai += __shfl_xor(ai, 1, 64);
    ar += __shfl_xor(ar, 2, 64);  ai += __shfl_xor(ai, 2, 64);
    ar += __shfl_xor(ar, 4, 64);  ai += __shfl_xor(ai, 4, 64);
    ar += __shfl_xor(ar, 8, 64);  ai += __shfl_xor(ai, 8, 64);
    ar += __shfl_xor(ar, 16, 64); ai += __shfl_xor(ai, 16, 64);
    ar += __shfl_xor(ar, 32, 64); ai += __shfl_xor(ai, 32, 64);
    int wv = tid >> 6;
    if ((tid & 63) == 0) { red[2 * wv] = ar; red[2 * wv + 1] = ai; }
    __syncthreads();
    if (tid == 0) {
      ar = red[0] + red[2] + red[4] + red[6];
      ai = red[1] + red[3] + red[5] + red[7];
      float rev = (float)nd * exp2f(-(float)(16 * (j + 1) + q) * 0.0625f);
      rev -= floorf(rev);
      float sn, cs; __sincosf(rev * 6.28318530718f, &sn, &cs);
      float br = ar * cs - ai * sn;
      float bi = ar * sn + ai * cs;
      int Ncu = (32767 >> j) + 17;
      *(float2*)(ws + P.ab[j - 3] + ((q * 2 + b) * Ncu + nidx) * 2) = make_float2(br, bi);
    }
  } else {
    // ---- small path (j=3,4) ----
    int wv = tid >> 6, lane = tid & 63;
    int wid = (bx - LBLK) * 4 + wv;
    int j, base;
    if (wid < 4128) { j = 4; base = 0; } else { j = 3; base = 4128; }
    int rem = wid - base;
    int q = rem & 15, tile = rem >> 4;
    int ki = 16 * (j - 3) + q;
    int d = 1 << j, J2 = j2_of_q(q);
    int M1e = P.m1e[ki];
    const float* vt = ws + P.voff[ki];
    int r = lane >> 3, p = lane & 7;
    int nidx = tile * 8 + r;
    int nd = (nidx - J2) * d;
    int ustart = nd - M1e;                 // even
    int it0 = (-ustart) >> 4; if (it0 < 0) it0 = 0;
    int itend = ((T_LEN - 1 - ustart) >> 4) + 1;
    int niter = P.slot[ki] >> 4; if (niter > itend) niter = itend;
    float ar = 0.f, ai = 0.f;
    int it = it0;
    int pb = 2 * p;
    for (; it + 4 <= niter; it += 4) {
      int mt0 = pb + (it << 4);
      float4 v0 = *(const float4*)(vt + 2 * mt0);
      float4 v1 = *(const float4*)(vt + 2 * (mt0 + 16));
      float4 v2 = *(const float4*)(vt + 2 * (mt0 + 32));
      float4 v3 = *(const float4*)(vt + 2 * (mt0 + 48));
      int u0 = ustart + mt0, u1 = u0 + 16, u2 = u0 + 32, u3 = u0 + 48;
      int c0 = min(max(u0, 0), T_LEN - 2), c1 = min(max(u1, 0), T_LEN - 2);
      int c2 = min(max(u2, 0), T_LEN - 2), c3 = min(max(u3, 0), T_LEN - 2);
      float2 p0 = *(const float2*)(xb + c0);
      float2 p1 = *(const float2*)(xb + c1);
      float2 p2 = *(const float2*)(xb + c2);
      float2 p3 = *(const float2*)(xb + c3);
      bool k0 = (unsigned)u0 <= (unsigned)(T_LEN - 2);
      bool k1 = (unsigned)u1 <= (unsigned)(T_LEN - 2);
      bool k2 = (unsigned)u2 <= (unsigned)(T_LEN - 2);
      bool k3 = (unsigned)u3 <= (unsigned)(T_LEN - 2);
      float x00 = k0 ? p0.x : 0.f, x01 = k0 ? p0.y : 0.f;
      float x10 = k1 ? p1.x : 0.f, x11 = k1 ? p1.y : 0.f;
      float x20 = k2 ? p2.x : 0.f, x21 = k2 ? p2.y : 0.f;
      float x30 = k3 ? p3.x : 0.f, x31 = k3 ? p3.y : 0.f;
      ar += v0.x * x00; ai += v0.y * x00; ar += v0.z * x01; ai += v0.w * x01;
      ar += v1.x * x10; ai += v1.y * x10; ar += v1.z * x11; ai += v1.w * x11;
      ar += v2.x * x20; ai += v2.y * x20; ar += v2.z * x21; ai += v2.w * x21;
      ar += v3.x * x30; ai += v3.y * x30; ar += v3.z * x31; ai += v3.w * x31;
    }
    for (; it < niter; ++it) {
      int mt = pb + (it << 4);
      float4 v = *(const float4*)(vt + 2 * mt);
      int u = ustart + mt;
      int uc = min(max(u, 0), T_LEN - 2);
      float2 pq = *(const float2*)(xb + uc);
      bool ok = (unsigned)u <= (unsigned)(T_LEN - 2);
      float x0 = ok ? pq.x : 0.f, x1 = ok ? pq.y : 0.f;
      ar += v.x * x0; ai += v.y * x0; ar += v.z * x1; ai += v.w * x1;
    }
    ar += __shfl_xor(ar, 1, 64); ai += __shfl_xor(ai, 1, 64);
    ar += __shfl_xor(ar, 2, 64); ai += __shfl_xor(ai, 2, 64);
    ar += __shfl_xor(ar, 4, 64); ai += __shfl_xor(ai, 4, 64);
    if (p == 0) {
      float rev = (float)nd * exp2f(-(float)(16 * (j + 1) + q) * 0.0625f);
      rev -= floorf(rev);
      float sn, cs; __sincosf(rev * 6.28318530718f, &sn, &cs);
      float br = ar * cs - ai * sn;
      float bi = ar * sn + ai * cs;
      int Ncu = (32767 >> j) + 17;
      *(float2*)(ws + P.ab[j - 3] + ((q * 2 + b) * Ncu + nidx) * 2) = make_float2(br, bi);
    }
  }
}

// ---------------- stage 2: 4 outputs/thread, shared weight recurrence ----------------
__global__ __launch_bounds__(256) void k_stage2(const float* __restrict__ ws,
                                                float* __restrict__ out, SParams P) {
  int k = KDIR + blockIdx.y;
  int j = k >> 4, q = k & 15;
  int b = blockIdx.z;
  int d = 1 << j;
  int J2 = j2_of_q(q);
  float sig = 2.f * exp2f((float)(16 * j + q) * 0.0625f);
  float s2 = sig * 0.5f;
  int Ncu = (32767 >> j) + 17;
  const float* A = ws + P.ab[j - 3] + (q * 2 + b) * Ncu * 2;
  int t0 = blockIdx.x * 256 + threadIdx.x;   // [0, 8192); outputs t0 + 8192*i
  int phi = t0 & (d - 1);
  int nb0 = t0 >> j;
  int step = 8192 >> j;                      // same phi at t0 + 8192*i
  int ntap = 2 * J2 + 1;
  float fd = (float)d;
  float inv2 = 1.f / (s2 * s2);
  float u0 = (float)(phi + J2 * d);
  float eg = __expf(-0.5f * u0 * u0 * inv2);
  float mf = __expf((fd * u0 - 0.5f * fd * fd) * inv2);
  float qf = __expf(-fd * fd * inv2);
  float Z = 0.f;
  float sr0 = 0.f, si0 = 0.f, sr1 = 0.f, si1 = 0.f;
  float sr2 = 0.f, si2 = 0.f, sr3 = 0.f, si3 = 0.f;
  const float* Ap = A + 2 * nb0;
  for (int rr = 0; rr < ntap; ++rr) {
    float w = eg; eg *= mf; mf *= qf; Z += w;
    float2 a0 = *(const float2*)(Ap + 2 * rr);
    float2 a1 = *(const float2*)(Ap + 2 * (rr + step));
    float2 a2 = *(const float2*)(Ap + 2 * (rr + 2 * step));
    float2 a3 = *(const float2*)(Ap + 2 * (rr + 3 * step));
    sr0 += w * a0.x; si0 += w * a0.y;
    sr1 += w * a1.x; si1 += w * a1.y;
    sr2 += w * a2.x; si2 += w * a2.y;
    sr3 += w * a3.x; si3 += w * a3.y;
  }
  float zi = 1.f / Z;
  size_t ob = (size_t)(b * NK + k) * T_LEN + t0;
  out[ob]         = sqrtf(sr0 * sr0 + si0 * si0) * zi;
  out[ob + 8192]  = sqrtf(sr1 * sr1 + si1 * si1) * zi;
  out[ob + 16384] = sqrtf(sr2 * sr2 + si2 * si2) * zi;
  out[ob + 24576] = sqrtf(sr3 * sr3 + si3 * si3) * zi;
}

// ---------------- direct exact conv for j<=2 ----------------
__global__ __launch_bounds__(256) void k_direct(const float* __restrict__ x,
                                               const float* __restrict__ fr,
                                               const float* __restrict__ fi,
                                               float* __restrict__ out, int Lmax) {
  int k = blockIdx.y;
  int b = blockIdx.z;
  int t0 = blockIdx.x * 1024;
  int j = k >> 4, q = k & 15;
  int M = (int)ceil(6.0 * exp2((double)j + (double)q * 0.0625)) + 2; // >= true M; extra taps are 0
  int P = Lmax >> 1;
  __shared__ float xs[1024 + 2 * MAXM];
  __shared__ float frs[2 * MAXM + 1], fis[2 * MAXM + 1];
  int tid = threadIdx.x;
  int xlen = 1024 + 2 * M;
  const float* xb = x + b * T_LEN;
  for (int i = tid; i < xlen; i += 256) {
    int u = t0 - M + i;
    xs[i] = (u >= 0 && u < T_LEN) ? xb[u] : 0.f;
  }
  const float* frk = fr + (size_t)k * Lmax + (P - M);
  const float* fik = fi + (size_t)k * Lmax + (P - M);
  int tl = 2 * M + 1;
  for (int i = tid; i < tl; i += 256) { frs[i] = frk[i]; fis[i] = fik[i]; }
  __syncthreads();
  float ar[4] = {0.f, 0.f, 0.f, 0.f}, ai[4] = {0.f, 0.f, 0.f, 0.f};
  for (int tau = 0; tau < tl; ++tau) {
    float wr = frs[tau], wi = fis[tau];
    #pragma unroll
    for (int tt = 0; tt < 4; ++tt) {
      float xv = xs[tid + tt * 256 + tau];
      ar[tt] += wr * xv; ai[tt] += wi * xv;
    }
  }
  size_t ob = (size_t)(b * NK + k) * T_LEN + t0 + tid;
  #pragma unroll
  for (int tt = 0; tt < 4; ++tt)
    out[ob + tt * 256] = sqrtf(ar[tt] * ar[tt] + ai[tt] * ai[tt]);
}

// ---------------- launch ----------------
extern "C" void kernel_launch(void* const* d_in, const int* in_sizes, int n_in,
                              void* d_out, int out_size, void* d_ws, size_t ws_size,
                              hipStream_t stream) {
  const float* x  = (const float*)d_in[0];
  const float* fr = (const float*)d_in[1];
  const float* fi = (const float*)d_in[2];
  float* out = (float*)d_out;
  float* ws  = (float*)d_ws;
  int Lmax = in_sizes[1] / NK;   // 47069

  // host-side geometry (pure CPU math, deterministic, graph-capture-safe)
  SParams Pm;
  int cur = 0, maxslot = 0;
  for (int ki = 0; ki < 144; ++ki) {
    int j = (ki + 48) >> 4, q = ki & 15;
    double sig = 2.0 * exp2(((double)(16 * j + q)) / 16.0);
    double s1 = sig * 0.86602540378443864676;
    int M1 = (int)ceil(3.5 * s1);
    int M1e = (M1 + 1) & ~1;
    int R = (j >= 5) ? 512 : 16;              // tap granularity: large path 512, small 16
    int slotc = (2 * M1e + 2 + R - 1) & ~(R - 1);
    Pm.m1e[ki] = M1e;
    Pm.voff[ki] = cur;
    Pm.slot[ki] = slotc;
    if (slotc > maxslot) maxslot = slotc;
    cur += 2 * slotc;
  }
  for (int j = 3; j <= 11; ++j) {
    Pm.ab[j - 3] = cur;
    cur += 32 * ((32767 >> j) + 17) * 2;   // 16q * 2b * Ncu * 2 words
  }

  k_vtab<<<dim3((maxslot + 255) / 256, 144), dim3(256), 0, stream>>>(ws, Pm);
  k_s1<<<dim3(GRIDX, NB), dim3(256), 0, stream>>>(x, ws, Pm);
  k_direct<<<dim3(T_LEN / 1024, KDIR, NB), dim3(256), 0, stream>>>(x, fr, fi, out, Lmax);
  k_stage2<<<dim3(T_LEN / (256 * 4), NK - KDIR, NB), dim3(256), 0, stream>>>(ws, out, Pm);
}

// Round 6
// 253.525 us; speedup vs baseline: 1.2410x; 1.1484x over previous
//
#include <hip/hip_runtime.h>
#include <math.h>

// ---------------- problem constants ----------------
#define T_LEN   32768
#define NK      192
#define NB      2
#define KDIR    48            // k < KDIR (j<=2): exact direct conv path
#define MAXM    56            // max half-support for direct path (true max 50)
#define BBLK    9216          // block-path blocks (j=7..11), one output each, both batches
#define WBLK    3872          // wave-path blocks (j=3..6), 4 waves x 8 outputs, both batches
#define GRIDX   (BBLK + WBLK)

struct SParams {
  int m1e[144];   // even half-support of stage-1 kernel per k-48
  int voff[144];  // v-table word offset per k-48
  int slot[144];  // padded complex tap count per k-48 (zero-filled tail)
  int ab[9];      // A-arena word base per octave j-3
};

__device__ __forceinline__ int j2_of_q(int q) {
  // ceil(3.25 * 2^(q/16)) : {4,...,4,5,...,5,6,...,6,7}
  return 4 + (q >= 5) + (q >= 10) + (q >= 15);
}

// ---------------- v-table: v[m] = g1(m) * e^{i*omega*m} / N1 ----------------
__global__ __launch_bounds__(256) void k_vtab(float* __restrict__ ws, SParams P) {
  int ki = blockIdx.y;                 // 0..143
  int slotc = P.slot[ki];
  int M1e = P.m1e[ki];
  float* dst = ws + P.voff[ki];
  int nent = 2 * M1e + 2;              // m in [-M1e, M1e+1]
  int k = ki + 48;
  int j = k >> 4, q = k & 15;
  float sig = 2.f * exp2f((float)(16 * j + q) * 0.0625f);
  float s1 = sig * 0.86602540378f;
  float gc = -0.5f / (s1 * s1);
  float om = 6.28318530718f / sig;
  float norm = 1.f / (2.50662827463f * s1 * erff((float)M1e / (1.41421356237f * s1)));
  #pragma unroll
  for (int e0 = 0; e0 < 4; ++e0) {
    int e = blockIdx.x * 1024 + e0 * 256 + threadIdx.x;
    if (e >= slotc) continue;
    if (e >= nent) { dst[2 * e] = 0.f; dst[2 * e + 1] = 0.f; continue; }
    float mm = (float)(e - M1e);
    float g = __expf(gc * mm * mm) * norm;
    float sn, cs; __sincosf(om * mm, &sn, &cs);
    dst[2 * e] = g * cs;
    dst[2 * e + 1] = g * sn;
  }
}

// ---------------- merged stage 1, both batches per block ----------------
// Block path (j=7..11): one output per 256-thread block, 512 taps/iter, 4x unroll.
// Wave path (j=3..6): wave = 8 phases x 8 outputs, 16 taps/iter, 4x unroll.
__global__ __launch_bounds__(256) void k_s1(const float* __restrict__ x,
                                            float* __restrict__ ws, SParams P) {
  __shared__ float red[16];
  const float* xb0 = x;
  const float* xb1 = x + T_LEN;
  int bx = blockIdx.x;
  int tid = threadIdx.x;

  if (bx < BBLK) {
    // ---- block path (j=7..11), deepest first ----
    int j, base;
    if (bx < 512)       { j = 11; base = 0; }
    else if (bx < 1280) { j = 10; base = 512; }
    else if (bx < 2560) { j = 9;  base = 1280; }
    else if (bx < 4864) { j = 8;  base = 2560; }
    else                { j = 7;  base = 4864; }
    int rem = bx - base;
    int q = rem & 15, nidx = rem >> 4;
    int ki = 16 * (j - 3) + q;
    int d = 1 << j, J2 = j2_of_q(q);
    int M1e = P.m1e[ki];
    const float* vt = ws + P.voff[ki];
    int nd = (nidx - J2) * d;
    int ustart = nd - M1e;                  // even
    int it0 = (-ustart) >> 9; if (it0 < 0) it0 = 0;
    int itend = ((T_LEN - 1 - ustart) >> 9) + 1;
    int niter = P.slot[ki] >> 9; if (niter > itend) niter = itend;
    float ar0 = 0.f, ai0 = 0.f, ar1 = 0.f, ai1 = 0.f;
    int it = it0;
    for (; it + 4 <= niter; it += 4) {
      int mt0 = 2 * tid + (it << 9);
      float4 v0 = *(const float4*)(vt + 2 * mt0);
      float4 v1 = *(const float4*)(vt + 2 * (mt0 + 512));
      float4 v2 = *(const float4*)(vt + 2 * (mt0 + 1024));
      float4 v3 = *(const float4*)(vt + 2 * (mt0 + 1536));
      int u0 = ustart + mt0, u1 = u0 + 512, u2 = u0 + 1024, u3 = u0 + 1536;
      int c0 = min(max(u0, 0), T_LEN - 2), c1 = min(max(u1, 0), T_LEN - 2);
      int c2 = min(max(u2, 0), T_LEN - 2), c3 = min(max(u3, 0), T_LEN - 2);
      float2 a0 = *(const float2*)(xb0 + c0);
      float2 a1 = *(const float2*)(xb0 + c1);
      float2 a2 = *(const float2*)(xb0 + c2);
      float2 a3 = *(const float2*)(xb0 + c3);
      float2 b0 = *(const float2*)(xb1 + c0);
      float2 b1 = *(const float2*)(xb1 + c1);
      float2 b2 = *(const float2*)(xb1 + c2);
      float2 b3 = *(const float2*)(xb1 + c3);
      bool k0 = (unsigned)u0 <= (unsigned)(T_LEN - 2);
      bool k1 = (unsigned)u1 <= (unsigned)(T_LEN - 2);
      bool k2 = (unsigned)u2 <= (unsigned)(T_LEN - 2);
      bool k3 = (unsigned)u3 <= (unsigned)(T_LEN - 2);
      float xa00 = k0 ? a0.x : 0.f, xa01 = k0 ? a0.y : 0.f;
      float xa10 = k1 ? a1.x : 0.f, xa11 = k1 ? a1.y : 0.f;
      float xa20 = k2 ? a2.x : 0.f, xa21 = k2 ? a2.y : 0.f;
      float xa30 = k3 ? a3.x : 0.f, xa31 = k3 ? a3.y : 0.f;
      float xb00 = k0 ? b0.x : 0.f, xb01 = k0 ? b0.y : 0.f;
      float xb10 = k1 ? b1.x : 0.f, xb11 = k1 ? b1.y : 0.f;
      float xb20 = k2 ? b2.x : 0.f, xb21 = k2 ? b2.y : 0.f;
      float xb30 = k3 ? b3.x : 0.f, xb31 = k3 ? b3.y : 0.f;
      ar0 += v0.x * xa00; ai0 += v0.y * xa00; ar0 += v0.z * xa01; ai0 += v0.w * xa01;
      ar1 += v0.x * xb00; ai1 += v0.y * xb00; ar1 += v0.z * xb01; ai1 += v0.w * xb01;
      ar0 += v1.x * xa10; ai0 += v1.y * xa10; ar0 += v1.z * xa11; ai0 += v1.w * xa11;
      ar1 += v1.x * xb10; ai1 += v1.y * xb10; ar1 += v1.z * xb11; ai1 += v1.w * xb11;
      ar0 += v2.x * xa20; ai0 += v2.y * xa20; ar0 += v2.z * xa21; ai0 += v2.w * xa21;
      ar1 += v2.x * xb20; ai1 += v2.y * xb20; ar1 += v2.z * xb21; ai1 += v2.w * xb21;
      ar0 += v3.x * xa30; ai0 += v3.y * xa30; ar0 += v3.z * xa31; ai0 += v3.w * xa31;
      ar1 += v3.x * xb30; ai1 += v3.y * xb30; ar1 += v3.z * xb31; ai1 += v3.w * xb31;
    }
    for (; it < niter; ++it) {
      int mt = 2 * tid + (it << 9);
      float4 v = *(const float4*)(vt + 2 * mt);
      int u = ustart + mt;
      int uc = min(max(u, 0), T_LEN - 2);
      float2 pa = *(const float2*)(xb0 + uc);
      float2 pb = *(const float2*)(xb1 + uc);
      bool ok = (unsigned)u <= (unsigned)(T_LEN - 2);
      float x0 = ok ? pa.x : 0.f, x1 = ok ? pa.y : 0.f;
      float y0 = ok ? pb.x : 0.f, y1 = ok ? pb.y : 0.f;
      ar0 += v.x * x0; ai0 += v.y * x0; ar0 += v.z * x1; ai0 += v.w * x1;
      ar1 += v.x * y0; ai1 += v.y * y0; ar1 += v.z * y1; ai1 += v.w * y1;
    }
#define RED4(s_) ar0 += __shfl_xor(ar0, s_, 64); ai0 += __shfl_xor(ai0, s_, 64); \
                 ar1 += __shfl_xor(ar1, s_, 64); ai1 += __shfl_xor(ai1, s_, 64);
    RED4(1) RED4(2) RED4(4) RED4(8) RED4(16) RED4(32)
#undef RED4
    int wv = tid >> 6;
    if ((tid & 63) == 0) {
      red[4 * wv] = ar0; red[4 * wv + 1] = ai0;
      red[4 * wv + 2] = ar1; red[4 * wv + 3] = ai1;
    }
    __syncthreads();
    if (tid == 0) {
      ar0 = red[0] + red[4] + red[8] + red[12];
      ai0 = red[1] + red[5] + red[9] + red[13];
      ar1 = red[2] + red[6] + red[10] + red[14];
      ai1 = red[3] + red[7] + red[11] + red[15];
      float rev = (float)nd * exp2f(-(float)(16 * (j + 1) + q) * 0.0625f);
      rev -= floorf(rev);
      float sn, cs; __sincosf(rev * 6.28318530718f, &sn, &cs);
      int Ncu = (32767 >> j) + 17;
      float* ap = ws + P.ab[j - 3] + (q * 2) * Ncu * 2;
      *(float2*)(ap + 2 * nidx) = make_float2(ar0 * cs - ai0 * sn, ar0 * sn + ai0 * cs);
      *(float2*)(ap + 2 * (Ncu + nidx)) = make_float2(ar1 * cs - ai1 * sn, ar1 * sn + ai1 * cs);
    }
  } else {
    // ---- wave path (j=3..6): 8 phases x 8 outputs per wave ----
    int wv = tid >> 6, lane = tid & 63;
    int wid = (bx - BBLK) * 4 + wv;
    int j, base;
    if (wid < 1056)      { j = 6; base = 0; }
    else if (wid < 3136) { j = 5; base = 1056; }
    else if (wid < 7264) { j = 4; base = 3136; }
    else                 { j = 3; base = 7264; }
    int rem = wid - base;
    int q = rem & 15, tile = rem >> 4;
    int ki = 16 * (j - 3) + q;
    int d = 1 << j, J2 = j2_of_q(q);
    int M1e = P.m1e[ki];
    const float* vt = ws + P.voff[ki];
    int r = lane >> 3, p = lane & 7;
    int nidx = tile * 8 + r;
    int nd = (nidx - J2) * d;
    int ustart = nd - M1e;                 // even
    int it0 = (-ustart) >> 4; if (it0 < 0) it0 = 0;
    int itend = ((T_LEN - 1 - ustart) >> 4) + 1;
    int niter = P.slot[ki] >> 4; if (niter > itend) niter = itend;
    float ar0 = 0.f, ai0 = 0.f, ar1 = 0.f, ai1 = 0.f;
    int it = it0;
    int pb2 = 2 * p;
    for (; it + 4 <= niter; it += 4) {
      int mt0 = pb2 + (it << 4);
      float4 v0 = *(const float4*)(vt + 2 * mt0);
      float4 v1 = *(const float4*)(vt + 2 * (mt0 + 16));
      float4 v2 = *(const float4*)(vt + 2 * (mt0 + 32));
      float4 v3 = *(const float4*)(vt + 2 * (mt0 + 48));
      int u0 = ustart + mt0, u1 = u0 + 16, u2 = u0 + 32, u3 = u0 + 48;
      int c0 = min(max(u0, 0), T_LEN - 2), c1 = min(max(u1, 0), T_LEN - 2);
      int c2 = min(max(u2, 0), T_LEN - 2), c3 = min(max(u3, 0), T_LEN - 2);
      float2 a0 = *(const float2*)(xb0 + c0);
      float2 a1 = *(const float2*)(xb0 + c1);
      float2 a2 = *(const float2*)(xb0 + c2);
      float2 a3 = *(const float2*)(xb0 + c3);
      float2 b0 = *(const float2*)(xb1 + c0);
      float2 b1 = *(const float2*)(xb1 + c1);
      float2 b2 = *(const float2*)(xb1 + c2);
      float2 b3 = *(const float2*)(xb1 + c3);
      bool k0 = (unsigned)u0 <= (unsigned)(T_LEN - 2);
      bool k1 = (unsigned)u1 <= (unsigned)(T_LEN - 2);
      bool k2 = (unsigned)u2 <= (unsigned)(T_LEN - 2);
      bool k3 = (unsigned)u3 <= (unsigned)(T_LEN - 2);
      float xa00 = k0 ? a0.x : 0.f, xa01 = k0 ? a0.y : 0.f;
      float xa10 = k1 ? a1.x : 0.f, xa11 = k1 ? a1.y : 0.f;
      float xa20 = k2 ? a2.x : 0.f, xa21 = k2 ? a2.y : 0.f;
      float xa30 = k3 ? a3.x : 0.f, xa31 = k3 ? a3.y : 0.f;
      float xb00 = k0 ? b0.x : 0.f, xb01 = k0 ? b0.y : 0.f;
      float xb10 = k1 ? b1.x : 0.f, xb11 = k1 ? b1.y : 0.f;
      float xb20 = k2 ? b2.x : 0.f, xb21 = k2 ? b2.y : 0.f;
      float xb30 = k3 ? b3.x : 0.f, xb31 = k3 ? b3.y : 0.f;
      ar0 += v0.x * xa00; ai0 += v0.y * xa00; ar0 += v0.z * xa01; ai0 += v0.w * xa01;
      ar1 += v0.x * xb00; ai1 += v0.y * xb00; ar1 += v0.z * xb01; ai1 += v0.w * xb01;
      ar0 += v1.x * xa10; ai0 += v1.y * xa10; ar0 += v1.z * xa11; ai0 += v1.w * xa11;
      ar1 += v1.x * xb10; ai1 += v1.y * xb10; ar1 += v1.z * xb11; ai1 += v1.w * xb11;
      ar0 += v2.x * xa20; ai0 += v2.y * xa20; ar0 += v2.z * xa21; ai0 += v2.w * xa21;
      ar1 += v2.x * xb20; ai1 += v2.y * xb20; ar1 += v2.z * xb21; ai1 += v2.w * xb21;
      ar0 += v3.x * xa30; ai0 += v3.y * xa30; ar0 += v3.z * xa31; ai0 += v3.w * xa31;
      ar1 += v3.x * xb30; ai1 += v3.y * xb30; ar1 += v3.z * xb31; ai1 += v3.w * xb31;
    }
    for (; it < niter; ++it) {
      int mt = pb2 + (it << 4);
      float4 v = *(const float4*)(vt + 2 * mt);
      int u = ustart + mt;
      int uc = min(max(u, 0), T_LEN - 2);
      float2 pa = *(const float2*)(xb0 + uc);
      float2 pbv = *(const float2*)(xb1 + uc);
      bool ok = (unsigned)u <= (unsigned)(T_LEN - 2);
      float x0 = ok ? pa.x : 0.f, x1 = ok ? pa.y : 0.f;
      float y0 = ok ? pbv.x : 0.f, y1 = ok ? pbv.y : 0.f;
      ar0 += v.x * x0; ai0 += v.y * x0; ar0 += v.z * x1; ai0 += v.w * x1;
      ar1 += v.x * y0; ai1 += v.y * y0; ar1 += v.z * y1; ai1 += v.w * y1;
    }
#define RED4(s_) ar0 += __shfl_xor(ar0, s_, 64); ai0 += __shfl_xor(ai0, s_, 64); \
                 ar1 += __shfl_xor(ar1, s_, 64); ai1 += __shfl_xor(ai1, s_, 64);
    RED4(1) RED4(2) RED4(4)
#undef RED4
    if (p == 0) {
      float rev = (float)nd * exp2f(-(float)(16 * (j + 1) + q) * 0.0625f);
      rev -= floorf(rev);
      float sn, cs; __sincosf(rev * 6.28318530718f, &sn, &cs);
      int Ncu = (32767 >> j) + 17;
      float* ap = ws + P.ab[j - 3] + (q * 2) * Ncu * 2;
      *(float2*)(ap + 2 * nidx) = make_float2(ar0 * cs - ai0 * sn, ar0 * sn + ai0 * cs);
      *(float2*)(ap + 2 * (Ncu + nidx)) = make_float2(ar1 * cs - ai1 * sn, ar1 * sn + ai1 * cs);
    }
  }
}

// ---------------- stage 2: 8 outputs/thread (4 t-pos x 2 batches) ----------------
__global__ __launch_bounds__(256) void k_stage2(const float* __restrict__ ws,
                                                float* __restrict__ out, SParams P) {
  int k = KDIR + blockIdx.y;
  int j = k >> 4, q = k & 15;
  int d = 1 << j;
  int J2 = j2_of_q(q);
  float sig = 2.f * exp2f((float)(16 * j + q) * 0.0625f);
  float s2 = sig * 0.5f;
  int Ncu = (32767 >> j) + 17;
  const float* A0 = ws + P.ab[j - 3] + (q * 2) * Ncu * 2;
  const float* A1 = A0 + Ncu * 2;
  int t0 = blockIdx.x * 256 + threadIdx.x;   // [0, 8192); outputs t0 + 8192*i
  int phi = t0 & (d - 1);
  int nb0 = t0 >> j;
  int step = 8192 >> j;                      // same phi at t0 + 8192*i
  int ntap = 2 * J2 + 1;
  float fd = (float)d;
  float inv2 = 1.f / (s2 * s2);
  float u0 = (float)(phi + J2 * d);
  float eg = __expf(-0.5f * u0 * u0 * inv2);
  float mf = __expf((fd * u0 - 0.5f * fd * fd) * inv2);
  float qf = __expf(-fd * fd * inv2);
  float Z = 0.f;
  float sr0 = 0.f, si0 = 0.f, sr1 = 0.f, si1 = 0.f;
  float sr2 = 0.f, si2 = 0.f, sr3 = 0.f, si3 = 0.f;
  float tr0 = 0.f, ti0 = 0.f, tr1 = 0.f, ti1 = 0.f;
  float tr2 = 0.f, ti2 = 0.f, tr3 = 0.f, ti3 = 0.f;
  const float* Ap0 = A0 + 2 * nb0;
  const float* Ap1 = A1 + 2 * nb0;
  for (int rr = 0; rr < ntap; ++rr) {
    float w = eg; eg *= mf; mf *= qf; Z += w;
    float2 a0 = *(const float2*)(Ap0 + 2 * rr);
    float2 a1 = *(const float2*)(Ap0 + 2 * (rr + step));
    float2 a2 = *(const float2*)(Ap0 + 2 * (rr + 2 * step));
    float2 a3 = *(const float2*)(Ap0 + 2 * (rr + 3 * step));
    float2 b0 = *(const float2*)(Ap1 + 2 * rr);
    float2 b1 = *(const float2*)(Ap1 + 2 * (rr + step));
    float2 b2 = *(const float2*)(Ap1 + 2 * (rr + 2 * step));
    float2 b3 = *(const float2*)(Ap1 + 2 * (rr + 3 * step));
    sr0 += w * a0.x; si0 += w * a0.y; sr1 += w * a1.x; si1 += w * a1.y;
    sr2 += w * a2.x; si2 += w * a2.y; sr3 += w * a3.x; si3 += w * a3.y;
    tr0 += w * b0.x; ti0 += w * b0.y; tr1 += w * b1.x; ti1 += w * b1.y;
    tr2 += w * b2.x; ti2 += w * b2.y; tr3 += w * b3.x; ti3 += w * b3.y;
  }
  float zi = 1.f / Z;
  size_t ob0 = (size_t)k * T_LEN + t0;
  size_t ob1 = (size_t)(NK + k) * T_LEN + t0;
  out[ob0]         = sqrtf(sr0 * sr0 + si0 * si0) * zi;
  out[ob0 + 8192]  = sqrtf(sr1 * sr1 + si1 * si1) * zi;
  out[ob0 + 16384] = sqrtf(sr2 * sr2 + si2 * si2) * zi;
  out[ob0 + 24576] = sqrtf(sr3 * sr3 + si3 * si3) * zi;
  out[ob1]         = sqrtf(tr0 * tr0 + ti0 * ti0) * zi;
  out[ob1 + 8192]  = sqrtf(tr1 * tr1 + ti1 * ti1) * zi;
  out[ob1 + 16384] = sqrtf(tr2 * tr2 + ti2 * ti2) * zi;
  out[ob1 + 24576] = sqrtf(tr3 * tr3 + ti3 * ti3) * zi;
}

// ---------------- direct exact conv for j<=2 ----------------
__global__ __launch_bounds__(256) void k_direct(const float* __restrict__ x,
                                               const float* __restrict__ fr,
                                               const float* __restrict__ fi,
                                               float* __restrict__ out, int Lmax) {
  int k = blockIdx.y;
  int b = blockIdx.z;
  int t0 = blockIdx.x * 1024;
  int j = k >> 4, q = k & 15;
  int M = (int)ceil(6.0 * exp2((double)j + (double)q * 0.0625)) + 2; // >= true M; extra taps are 0
  int P = Lmax >> 1;
  __shared__ float xs[1024 + 2 * MAXM];
  __shared__ float frs[2 * MAXM + 1], fis[2 * MAXM + 1];
  int tid = threadIdx.x;
  int xlen = 1024 + 2 * M;
  const float* xb = x + b * T_LEN;
  for (int i = tid; i < xlen; i += 256) {
    int u = t0 - M + i;
    xs[i] = (u >= 0 && u < T_LEN) ? xb[u] : 0.f;
  }
  const float* frk = fr + (size_t)k * Lmax + (P - M);
  const float* fik = fi + (size_t)k * Lmax + (P - M);
  int tl = 2 * M + 1;
  for (int i = tid; i < tl; i += 256) { frs[i] = frk[i]; fis[i] = fik[i]; }
  __syncthreads();
  float ar[4] = {0.f, 0.f, 0.f, 0.f}, ai[4] = {0.f, 0.f, 0.f, 0.f};
  for (int tau = 0; tau < tl; ++tau) {
    float wr = frs[tau], wi = fis[tau];
    #pragma unroll
    for (int tt = 0; tt < 4; ++tt) {
      float xv = xs[tid + tt * 256 + tau];
      ar[tt] += wr * xv; ai[tt] += wi * xv;
    }
  }
  size_t ob = (size_t)(b * NK + k) * T_LEN + t0 + tid;
  #pragma unroll
  for (int tt = 0; tt < 4; ++tt)
    out[ob + tt * 256] = sqrtf(ar[tt] * ar[tt] + ai[tt] * ai[tt]);
}

// ---------------- launch ----------------
extern "C" void kernel_launch(void* const* d_in, const int* in_sizes, int n_in,
                              void* d_out, int out_size, void* d_ws, size_t ws_size,
                              hipStream_t stream) {
  const float* x  = (const float*)d_in[0];
  const float* fr = (const float*)d_in[1];
  const float* fi = (const float*)d_in[2];
  float* out = (float*)d_out;
  float* ws  = (float*)d_ws;
  int Lmax = in_sizes[1] / NK;   // 47069

  // host-side geometry (pure CPU math, deterministic, graph-capture-safe)
  SParams Pm;
  int cur = 0, maxslot = 0;
  for (int ki = 0; ki < 144; ++ki) {
    int j = (ki + 48) >> 4, q = ki & 15;
    double sig = 2.0 * exp2(((double)(16 * j + q)) / 16.0);
    double s1 = sig * 0.86602540378443864676;
    int M1 = (int)ceil(3.5 * s1);
    int M1e = (M1 + 1) & ~1;
    int R = (j >= 7) ? 512 : 16;              // tap granularity: block path 512, wave 16
    int slotc = (2 * M1e + 2 + R - 1) & ~(R - 1);
    Pm.m1e[ki] = M1e;
    Pm.voff[ki] = cur;
    Pm.slot[ki] = slotc;
    if (slotc > maxslot) maxslot = slotc;
    cur += 2 * slotc;
  }
  for (int j = 3; j <= 11; ++j) {
    Pm.ab[j - 3] = cur;
    cur += 32 * ((32767 >> j) + 17) * 2;   // 16q * 2b * Ncu * 2 words
  }

  k_vtab<<<dim3((maxslot + 1023) / 1024, 144), dim3(256), 0, stream>>>(ws, Pm);
  k_s1<<<dim3(GRIDX), dim3(256), 0, stream>>>(x, ws, Pm);
  k_direct<<<dim3(T_LEN / 1024, KDIR, NB), dim3(256), 0, stream>>>(x, fr, fi, out, Lmax);
  k_stage2<<<dim3(T_LEN / (256 * 4), NK - KDIR), dim3(256), 0, stream>>>(ws, out, Pm);
}